// Round 1
// baseline (4514.938 us; speedup 1.0000x reference)
//
#include <hip/hip_runtime.h>
#include <math.h>

#define BTOT  65536
#define NN    6
#define EMBD  128
#define HIDD  256
#define PROJD 512
#define LAT2  128
#define TI    16
#define NTHR  1024
#define NEG   0.2f
#define MASKV (-1e9f)

// LDS: hbuf 96KB + stage 48KB = 144KB (<160KB) -> 1 block/CU, 16 waves.

template<int K, bool LAST>
__device__ __forceinline__ void gat_layer(
    float* hb, float* st,
    const float* __restrict__ W,
    const float* __restrict__ avec,
    int item, int lane, int tid,
    unsigned long long mz)
{
    const int c0 = lane << 2;           // 4 output cols per lane (covers 256)
    float wh[NN][4];
    #pragma unroll
    for (int i = 0; i < NN; ++i)
        #pragma unroll
        for (int c = 0; c < 4; ++c) wh[i][c] = 0.f;

    const float* hitem = hb + item * (NN * HIDD);   // [feat][node] layout

    // ---- Wh = h @ W, W staged in LDS 32-row chunks ----
    for (int k0 = 0; k0 < K; k0 += 32) {
        __syncthreads();
        {
            const int cc = (tid & 63) << 2;
            const int r0 = tid >> 6;           // 0..15
            *(float4*)(st + r0 * HIDD + cc) =
                *(const float4*)(W + (size_t)(k0 + r0) * HIDD + cc);
            *(float4*)(st + (r0 + 16) * HIDD + cc) =
                *(const float4*)(W + (size_t)(k0 + r0 + 16) * HIDD + cc);
        }
        __syncthreads();
        #pragma unroll
        for (int k = 0; k < 32; ++k) {
            const float* hr = hitem + (k0 + k) * NN;   // 6 contiguous floats
            float2 h01 = *(const float2*)(hr + 0);
            float2 h23 = *(const float2*)(hr + 2);
            float2 h45 = *(const float2*)(hr + 4);
            float av[NN] = {h01.x, h01.y, h23.x, h23.y, h45.x, h45.y};
            float4 bv = *(const float4*)(st + k * HIDD + c0);
            #pragma unroll
            for (int i = 0; i < NN; ++i) {
                wh[i][0] = fmaf(av[i], bv.x, wh[i][0]);
                wh[i][1] = fmaf(av[i], bv.y, wh[i][1]);
                wh[i][2] = fmaf(av[i], bv.z, wh[i][2]);
                wh[i][3] = fmaf(av[i], bv.w, wh[i][3]);
            }
        }
    }

    // ---- a_src/a_dst: partial dot + wave butterfly reduce ----
    float4 as4 = *(const float4*)(avec + c0);
    float4 ad4 = *(const float4*)(avec + HIDD + c0);
    float ps[NN], pd[NN];
    #pragma unroll
    for (int i = 0; i < NN; ++i) {
        ps[i] = wh[i][0]*as4.x + wh[i][1]*as4.y + wh[i][2]*as4.z + wh[i][3]*as4.w;
        pd[i] = wh[i][0]*ad4.x + wh[i][1]*ad4.y + wh[i][2]*ad4.z + wh[i][3]*ad4.w;
    }
    for (int off = 32; off > 0; off >>= 1) {
        #pragma unroll
        for (int i = 0; i < NN; ++i) {
            ps[i] += __shfl_xor(ps[i], off);
            pd[i] += __shfl_xor(pd[i], off);
        }
    }

    // ---- attention (lane-uniform, unnormalized-softmax aggregation) ----
    float rmax[NN];
    #pragma unroll
    for (int i = 0; i < NN; ++i) rmax[i] = -3.4e38f;
    #pragma unroll
    for (int i = 0; i < NN; ++i) {
        #pragma unroll
        for (int j = 0; j < NN; ++j) {
            float e = ps[i] + pd[j];
            e = (e > 0.f) ? e : NEG * e;
            if ((mz >> (i * 6 + j)) & 1ull) e = MASKV;
            rmax[i] = fmaxf(rmax[i], e);
        }
    }
    float rsum[NN] = {0.f, 0.f, 0.f, 0.f, 0.f, 0.f};
    float nh[NN][4];
    #pragma unroll
    for (int i = 0; i < NN; ++i)
        #pragma unroll
        for (int c = 0; c < 4; ++c) nh[i][c] = 0.f;

    #pragma unroll
    for (int j = 0; j < NN; ++j) {
        float s[NN];
        #pragma unroll
        for (int i = 0; i < NN; ++i) {
            float e = ps[i] + pd[j];
            e = (e > 0.f) ? e : NEG * e;
            if ((mz >> (i * 6 + j)) & 1ull) e = MASKV;
            s[i] = expf(e - rmax[i]);
            rsum[i] += s[i];
        }
        #pragma unroll
        for (int i = 0; i < NN; ++i) {
            nh[i][0] = fmaf(s[i], wh[j][0], nh[i][0]);
            nh[i][1] = fmaf(s[i], wh[j][1], nh[i][1]);
            nh[i][2] = fmaf(s[i], wh[j][2], nh[i][2]);
            nh[i][3] = fmaf(s[i], wh[j][3], nh[i][3]);
        }
    }

    // ---- normalize + relu + write back (wave-private region, no barrier) ----
    float* hout = hb + item * (NN * HIDD);
    #pragma unroll
    for (int i = 0; i < NN; ++i) {
        float rinv = 1.0f / rsum[i];
        if (LAST) {
            // transposed: [node][feat] == graph_repr layout
            float4 v;
            v.x = fmaxf(nh[i][0] * rinv, 0.f);
            v.y = fmaxf(nh[i][1] * rinv, 0.f);
            v.z = fmaxf(nh[i][2] * rinv, 0.f);
            v.w = fmaxf(nh[i][3] * rinv, 0.f);
            *(float4*)(hout + i * HIDD + c0) = v;
        } else {
            #pragma unroll
            for (int c = 0; c < 4; ++c)
                hout[(c0 + c) * NN + i] = fmaxf(nh[i][c] * rinv, 0.f);
        }
    }
}

__global__ __launch_bounds__(NTHR) void nge_fused(
    const int* __restrict__ numbers,
    const float* __restrict__ adj,
    const float* __restrict__ emb,
    const float* __restrict__ W0, const float* __restrict__ a0,
    const float* __restrict__ W1, const float* __restrict__ a1,
    const float* __restrict__ W2, const float* __restrict__ a2,
    const float* __restrict__ P1w, const float* __restrict__ P1b,
    const float* __restrict__ P2w, const float* __restrict__ P2b,
    float* __restrict__ out)
{
    __shared__ float hbuf[TI * NN * HIDD];   // 24576 floats = 96 KB
    __shared__ float stage[12288];           // 48 KB

    const int tid  = threadIdx.x;
    const int lane = tid & 63;
    const int item = tid >> 6;               // wave id == item id (GAT phases)
    const int bidx = blockIdx.x * TI + item;

    // ---- gather h0 = emb[numbers[b]] into [item][feat][node], feat<128 ----
    {
        int rows[NN];
        #pragma unroll
        for (int i = 0; i < NN; ++i) rows[i] = numbers[bidx * NN + i];
        float* hitem = hbuf + item * (NN * HIDD);
        #pragma unroll
        for (int i = 0; i < NN; ++i) {
            #pragma unroll
            for (int r = 0; r < 2; ++r) {
                int f = lane + (r << 6);
                hitem[f * NN + i] = emb[rows[i] * EMBD + f];
            }
        }
    }

    // ---- adj==0 mask, one bit per (i,j), built with one ballot ----
    unsigned long long mz;
    {
        float av = (lane < 36) ? adj[(size_t)bidx * 36 + lane] : 1.0f;
        mz = __ballot((lane < 36) && (av == 0.0f));
    }

    // ---- 3 GAT layers ----
    gat_layer<EMBD, false>(hbuf, stage, W0, a0, item, lane, tid, mz);
    gat_layer<HIDD, false>(hbuf, stage, W1, a1, item, lane, tid, mz);
    gat_layer<HIDD, true >(hbuf, stage, W2, a2, item, lane, tid, mz);

    // ---- P1: x = relu(gr @ P1w + P1b), gr = hbuf[item][node*256+feat] ----
    const int ct  = tid & 127;
    const int rt  = tid >> 7;        // 0..7 -> items {rt, rt+8}
    const int pc0 = ct << 2;         // 4 cols in [0,512)
    float acc[2][4];
    #pragma unroll
    for (int t = 0; t < 2; ++t)
        #pragma unroll
        for (int c = 0; c < 4; ++c) acc[t][c] = 0.f;

    for (int g0 = 0; g0 < NN * HIDD; g0 += 24) {
        __syncthreads();
        #pragma unroll
        for (int s = 0; s < 3; ++s) {
            int r = rt + 8 * s;
            *(float4*)(stage + r * PROJD + pc0) =
                *(const float4*)(P1w + (size_t)(g0 + r) * PROJD + pc0);
        }
        __syncthreads();
        #pragma unroll
        for (int r4 = 0; r4 < 24; r4 += 4) {
            float4 A0 = *(const float4*)(hbuf + rt * (NN * HIDD) + g0 + r4);
            float4 A1 = *(const float4*)(hbuf + (rt + 8) * (NN * HIDD) + g0 + r4);
            const float a0v[4] = {A0.x, A0.y, A0.z, A0.w};
            const float a1v[4] = {A1.x, A1.y, A1.z, A1.w};
            #pragma unroll
            for (int rr = 0; rr < 4; ++rr) {
                float4 bv = *(const float4*)(stage + (r4 + rr) * PROJD + pc0);
                acc[0][0] = fmaf(a0v[rr], bv.x, acc[0][0]);
                acc[0][1] = fmaf(a0v[rr], bv.y, acc[0][1]);
                acc[0][2] = fmaf(a0v[rr], bv.z, acc[0][2]);
                acc[0][3] = fmaf(a0v[rr], bv.w, acc[0][3]);
                acc[1][0] = fmaf(a1v[rr], bv.x, acc[1][0]);
                acc[1][1] = fmaf(a1v[rr], bv.y, acc[1][1]);
                acc[1][2] = fmaf(a1v[rr], bv.z, acc[1][2]);
                acc[1][3] = fmaf(a1v[rr], bv.w, acc[1][3]);
            }
        }
    }
    __syncthreads();   // all gr reads done before overwriting hbuf with x
    {
        float4 b1 = *(const float4*)(P1b + pc0);
        #pragma unroll
        for (int t = 0; t < 2; ++t) {
            int it = rt + 8 * t;
            float4 xv;
            xv.x = fmaxf(acc[t][0] + b1.x, 0.f);
            xv.y = fmaxf(acc[t][1] + b1.y, 0.f);
            xv.z = fmaxf(acc[t][2] + b1.z, 0.f);
            xv.w = fmaxf(acc[t][3] + b1.w, 0.f);
            *(float4*)(hbuf + it * PROJD + pc0) = xv;   // x[item][512]
        }
    }

    // ---- P2: latent = x @ P2w + P2b; split mu/logvar ----
    const int j0 = lane << 1;        // 2 cols in [0,128)
    float acc2x = 0.f, acc2y = 0.f;
    for (int g0 = 0; g0 < PROJD; g0 += 64) {
        __syncthreads();
        {
            int r  = tid >> 5;           // 0..31
            int cc = (tid & 31) << 2;    // 0..124
            *(float4*)(stage + r * LAT2 + cc) =
                *(const float4*)(P2w + (size_t)(g0 + r) * LAT2 + cc);
            *(float4*)(stage + (r + 32) * LAT2 + cc) =
                *(const float4*)(P2w + (size_t)(g0 + r + 32) * LAT2 + cc);
        }
        __syncthreads();
        const float* xit = hbuf + item * PROJD + g0;
        #pragma unroll
        for (int r4 = 0; r4 < 64; r4 += 4) {
            float4 A = *(const float4*)(xit + r4);
            const float av[4] = {A.x, A.y, A.z, A.w};
            #pragma unroll
            for (int rr = 0; rr < 4; ++rr) {
                float2 bv = *(const float2*)(stage + (r4 + rr) * LAT2 + j0);
                acc2x = fmaf(av[rr], bv.x, acc2x);
                acc2y = fmaf(av[rr], bv.y, acc2y);
            }
        }
    }
    {
        float o0 = acc2x + P2b[j0];
        float o1 = acc2y + P2b[j0 + 1];
        size_t base = (size_t)bidx * 64;
        float2 v; v.x = o0; v.y = o1;
        if (j0 < 64) {
            *(float2*)(out + base + j0) = v;                           // mu
        } else {
            *(float2*)(out + (size_t)BTOT * 64 + base + (j0 - 64)) = v; // logvar
        }
    }
}

extern "C" void kernel_launch(void* const* d_in, const int* in_sizes, int n_in,
                              void* d_out, int out_size, void* d_ws, size_t ws_size,
                              hipStream_t stream) {
    const int*   numbers = (const int*)  d_in[0];
    const float* adj     = (const float*)d_in[1];
    const float* emb     = (const float*)d_in[2];
    const float* W0      = (const float*)d_in[3];
    const float* a0      = (const float*)d_in[4];
    const float* W1      = (const float*)d_in[5];
    const float* a1      = (const float*)d_in[6];
    const float* W2      = (const float*)d_in[7];
    const float* a2      = (const float*)d_in[8];
    const float* P1w     = (const float*)d_in[9];
    const float* P1b     = (const float*)d_in[10];
    const float* P2w     = (const float*)d_in[11];
    const float* P2b     = (const float*)d_in[12];
    float* out = (float*)d_out;

    dim3 grid(BTOT / TI);   // 4096 blocks, 16 items each
    nge_fused<<<grid, NTHR, 0, stream>>>(numbers, adj, emb,
                                         W0, a0, W1, a1, W2, a2,
                                         P1w, P1b, P2w, P2b, out);
}